// Round 4
// baseline (263.539 us; speedup 1.0000x reference)
//
#include <hip/hip_runtime.h>
#include <hip/hip_bf16.h>

#define NBINS 10
#define C 128
#define U 4  // pairs per wave-iteration

// d_ws layout: [0..9] counts (u64), [10..19] sum_conf 32.32 fixed (u64),
//              [20..29] sum_acc (u64), [30] done-counter
__global__ __launch_bounds__(256) void ece_main_kernel(
    const float* __restrict__ logits, const int* __restrict__ targets,
    unsigned long long* __restrict__ gbins, float* __restrict__ out,
    int N, int nblocks) {
  __shared__ unsigned long long sbins[3 * NBINS];
  const int tid = threadIdx.x;
  for (int i = tid; i < 3 * NBINS; i += blockDim.x) sbins[i] = 0ull;
  __syncthreads();

  const int lane = tid & 63;
  const int half = lane >> 5;   // which row of each pair this lane works on
  const int hl = lane & 31;     // lane within the 32-lane half
  const int wavesPerBlock = blockDim.x >> 6;
  const int wid = blockIdx.x * wavesPerBlock + (tid >> 6);
  const int nwaves = gridDim.x * wavesPerBlock;
  const int npairs = N >> 1;
  const int stride = nwaves * U;

  float4 v[U];
  int tg[U];

  // prologue: load first batch
  {
    const int p0 = wid * U;
    if (p0 < npairs) {
      #pragma unroll
      for (int u = 0; u < U; ++u) {
        const int p = p0 + u;
        const int pc = p < npairs ? p : npairs - 1;
        v[u] = *reinterpret_cast<const float4*>(
            logits + (size_t)pc * (2 * C) + half * C + hl * 4);
        tg[u] = targets[pc * 2 + half];
      }
    }
  }

  for (int p0 = wid * U; p0 < npairs; p0 += stride) {
    // ---- prefetch next batch (stays in flight during the whole chain) ----
    float4 w[U];
    int tw[U];
    const int pn = p0 + stride;
    const bool hasNext = pn < npairs;
    if (hasNext) {
      #pragma unroll
      for (int u = 0; u < U; ++u) {
        const int p = pn + u;
        const int pc = p < npairs ? p : npairs - 1;
        w[u] = *reinterpret_cast<const float4*>(
            logits + (size_t)pc * (2 * C) + half * C + hl * 4);
        tw[u] = targets[pc * 2 + half];
      }
    }

    // ---- process current batch ----
    float m[U], lm[U];
    int col[U];
    #pragma unroll
    for (int u = 0; u < U; ++u) {
      float mm = v[u].x; int c = 0;
      if (v[u].y > mm) { mm = v[u].y; c = 1; }
      if (v[u].z > mm) { mm = v[u].z; c = 2; }
      if (v[u].w > mm) { mm = v[u].w; c = 3; }
      m[u] = mm; lm[u] = mm; col[u] = (hl << 2) + c;
    }
    #pragma unroll
    for (int off = 1; off <= 16; off <<= 1) {
      #pragma unroll
      for (int u = 0; u < U; ++u) m[u] = fmaxf(m[u], __shfl_xor(m[u], off));
    }
    int wcol[U];
    #pragma unroll
    for (int u = 0; u < U; ++u) {
      const unsigned long long b = __ballot(lm[u] == m[u]);
      const unsigned slice = (unsigned)(b >> (half << 5));
      const int srcl = (half << 5) + (__ffs(slice) - 1);
      wcol[u] = __shfl(col[u], srcl);
    }
    float s[U];
    #pragma unroll
    for (int u = 0; u < U; ++u)
      s[u] = (__expf(v[u].x - m[u]) + __expf(v[u].y - m[u])) +
             (__expf(v[u].z - m[u]) + __expf(v[u].w - m[u]));
    #pragma unroll
    for (int off = 1; off <= 16; off <<= 1) {
      #pragma unroll
      for (int u = 0; u < U; ++u) s[u] += __shfl_xor(s[u], off);
    }
    #pragma unroll
    for (int u = 0; u < U; ++u) {
      if ((p0 + u) < npairs && hl == 0) {
        const float conf = 1.0f / s[u];            // = max(softmax(row))
        int bin = (int)ceilf(conf * 10.0f) - 1;    // (k/10,(k+1)/10] -> k
        bin = min(max(bin, 0), NBINS - 1);
        const unsigned long long acc = (tg[u] == wcol[u]) ? 1ull : 0ull;
        const unsigned long long confq =
            (unsigned long long)((double)conf * 4294967296.0);
        atomicAdd(&sbins[bin], 1ull);
        atomicAdd(&sbins[NBINS + bin], confq);
        atomicAdd(&sbins[2 * NBINS + bin], acc);
      }
    }

    if (hasNext) {
      #pragma unroll
      for (int u = 0; u < U; ++u) { v[u] = w[u]; tg[u] = tw[u]; }
    }
  }

  // odd-N leftover row (not hit for N=262144)
  if ((N & 1) && wid == 0 && half == 0) {
    const int row = N - 1;
    const float4 x = *reinterpret_cast<const float4*>(
        logits + (size_t)row * C + hl * 4);
    float m = x.x; int c = 0;
    if (x.y > m) { m = x.y; c = 1; }
    if (x.z > m) { m = x.z; c = 2; }
    if (x.w > m) { m = x.w; c = 3; }
    const float lmv = m;
    const int col = (hl << 2) + c;
    #pragma unroll
    for (int off = 1; off <= 16; off <<= 1) m = fmaxf(m, __shfl_xor(m, off));
    const unsigned long long b = __ballot(lmv == m);
    const int srcl = __ffs((unsigned)b) - 1;
    const int wcol = __shfl(col, srcl);
    float s = (__expf(x.x - m) + __expf(x.y - m)) +
              (__expf(x.z - m) + __expf(x.w - m));
    #pragma unroll
    for (int off = 1; off <= 16; off <<= 1) s += __shfl_xor(s, off);
    if (hl == 0) {
      const float conf = 1.0f / s;
      int bin = (int)ceilf(conf * 10.0f) - 1;
      bin = min(max(bin, 0), NBINS - 1);
      const unsigned long long acc = (targets[row] == wcol) ? 1ull : 0ull;
      const unsigned long long confq =
          (unsigned long long)((double)conf * 4294967296.0);
      atomicAdd(&sbins[bin], 1ull);
      atomicAdd(&sbins[NBINS + bin], confq);
      atomicAdd(&sbins[2 * NBINS + bin], acc);
    }
  }

  // flush block partials to global
  __syncthreads();
  for (int i = tid; i < 3 * NBINS; i += blockDim.x) {
    unsigned long long vv = sbins[i];
    if (vv) atomicAdd(&gbins[i], vv);
  }
  __threadfence();
  __syncthreads();

  // last-block-done finalize (integer sums -> order-independent, deterministic)
  __shared__ int isLast;
  if (tid == 0) {
    unsigned* done = (unsigned*)&gbins[30];
    const unsigned old = __hip_atomic_fetch_add(done, 1u, __ATOMIC_ACQ_REL,
                                                __HIP_MEMORY_SCOPE_AGENT);
    isLast = (old == (unsigned)(nblocks - 1)) ? 1 : 0;
  }
  __syncthreads();
  if (isLast && tid < 16) {
    float per = 0.0f;
    if (tid < NBINS) {
      // atomic RMW reads -> coherent across XCDs
      const double cnt = (double)atomicAdd(&gbins[tid], 0ull);
      const double sc =
          (double)atomicAdd(&gbins[NBINS + tid], 0ull) * (1.0 / 4294967296.0);
      const double sa = (double)atomicAdd(&gbins[2 * NBINS + tid], 0ull);
      const double safe = cnt > 0.0 ? cnt : 1.0;
      const double avg_c = sc / safe;
      const double avg_a = sa / safe;
      const double prop = cnt / (double)N;
      per = (cnt > 0.0) ? (float)(fabs(avg_c - avg_a) * prop) : 0.0f;
    }
    #pragma unroll
    for (int off = 1; off < 16; off <<= 1) per += __shfl_xor(per, off);
    if (tid == 0) out[0] = per;
  }
}

extern "C" void kernel_launch(void* const* d_in, const int* in_sizes, int n_in,
                              void* d_out, int out_size, void* d_ws, size_t ws_size,
                              hipStream_t stream) {
  const float* logits = (const float*)d_in[0];
  const int* targets = (const int*)d_in[1];
  float* out = (float*)d_out;
  unsigned long long* gbins = (unsigned long long*)d_ws;

  const int N = in_sizes[1];  // 262144 rows

  // zero bins + done-counter (31 u64 slots)
  hipMemsetAsync(gbins, 0, 31 * sizeof(unsigned long long), stream);

  const int block = 256;  // 4 waves/block
  int grid = 2048;        // 8192 waves
  const int npairs = N >> 1;
  int maxGrid = (npairs + 4 * U - 1) / (4 * U);
  if (grid > maxGrid) grid = maxGrid > 0 ? maxGrid : 1;

  ece_main_kernel<<<grid, block, 0, stream>>>(logits, targets, gbins, out, N,
                                              grid);
}

// Round 5
// 125.327 us; speedup vs baseline: 2.1028x; 2.1028x over previous
//
#include <hip/hip_runtime.h>
#include <hip/hip_bf16.h>

#define NBINS 10
#define C 128
#define U 4  // pairs per wave (one-shot: each wave processes exactly U pairs)

// d_ws layout: [0..9] counts (u64), [10..19] sum_conf in 32.32 fixed point (u64),
//              [20..29] sum_acc (u64)

__global__ __launch_bounds__(256) void ece_main_kernel(
    const float* __restrict__ logits, const int* __restrict__ targets,
    unsigned long long* __restrict__ gbins, int N) {
  __shared__ unsigned long long sbins[3 * NBINS];
  const int tid = threadIdx.x;
  for (int i = tid; i < 3 * NBINS; i += blockDim.x) sbins[i] = 0ull;
  __syncthreads();

  const int lane = tid & 63;
  const int half = lane >> 5;   // which row of each pair this lane works on
  const int hl = lane & 31;     // lane index within the 32-lane half
  const int wavesPerBlock = blockDim.x >> 6;
  const int wid = blockIdx.x * wavesPerBlock + (tid >> 6);
  const int nwaves = gridDim.x * wavesPerBlock;

  const int npairs = N >> 1;

  // grid is sized so this loop executes at most once per wave (one-shot TLP):
  // fresh waves keep issuing loads while older waves run their reduce chains.
  for (int p0 = wid * U; p0 < npairs; p0 += nwaves * U) {
    float4 v[U];
    int pp[U];
    int tg[U];
    #pragma unroll
    for (int u = 0; u < U; ++u) {
      const int p = p0 + u;
      pp[u] = p < npairs ? p : npairs - 1;
      v[u] = *reinterpret_cast<const float4*>(
          logits + (size_t)pp[u] * (2 * C) + half * C + hl * 4);
      tg[u] = targets[pp[u] * 2 + half];
    }

    // in-lane max + first-occurrence argmax over 4 elements
    float m[U], lm[U];
    int col[U];
    #pragma unroll
    for (int u = 0; u < U; ++u) {
      float mm = v[u].x; int c = 0;
      if (v[u].y > mm) { mm = v[u].y; c = 1; }
      if (v[u].z > mm) { mm = v[u].z; c = 2; }
      if (v[u].w > mm) { mm = v[u].w; c = 3; }
      m[u] = mm; lm[u] = mm; col[u] = (hl << 2) + c;
    }

    // half-wave value max: U independent DPP chains interleaved
    #pragma unroll
    for (int off = 1; off <= 16; off <<= 1) {
      #pragma unroll
      for (int u = 0; u < U; ++u) m[u] = fmaxf(m[u], __shfl_xor(m[u], off));
    }

    // first-occurrence argmax via ballot (lowest flagged lane in this half)
    int wcol[U];
    #pragma unroll
    for (int u = 0; u < U; ++u) {
      const unsigned long long b = __ballot(lm[u] == m[u]);
      const unsigned slice = (unsigned)(b >> (half << 5));
      const int srcl = (half << 5) + (__ffs(slice) - 1);
      wcol[u] = __shfl(col[u], srcl);
    }

    // sum of exp(x - max): independent exps, then U interleaved add chains
    float s[U];
    #pragma unroll
    for (int u = 0; u < U; ++u)
      s[u] = (__expf(v[u].x - m[u]) + __expf(v[u].y - m[u])) +
             (__expf(v[u].z - m[u]) + __expf(v[u].w - m[u]));
    #pragma unroll
    for (int off = 1; off <= 16; off <<= 1) {
      #pragma unroll
      for (int u = 0; u < U; ++u) s[u] += __shfl_xor(s[u], off);
    }

    #pragma unroll
    for (int u = 0; u < U; ++u) {
      if ((p0 + u) < npairs && hl == 0) {
        const float conf = 1.0f / s[u];            // = max(softmax(row))
        int bin = (int)ceilf(conf * 10.0f) - 1;    // (k/10,(k+1)/10] -> k
        bin = min(max(bin, 0), NBINS - 1);
        const unsigned long long acc = (tg[u] == wcol[u]) ? 1ull : 0ull;
        const unsigned long long confq =
            (unsigned long long)((double)conf * 4294967296.0);
        atomicAdd(&sbins[bin], 1ull);
        atomicAdd(&sbins[NBINS + bin], confq);
        atomicAdd(&sbins[2 * NBINS + bin], acc);
      }
    }
  }

  // odd-N leftover row (not hit for N=262144; kept for generality)
  if ((N & 1) && wid == 0 && half == 0) {
    const int row = N - 1;
    const float4 x = *reinterpret_cast<const float4*>(
        logits + (size_t)row * C + hl * 4);
    float m = x.x; int c = 0;
    if (x.y > m) { m = x.y; c = 1; }
    if (x.z > m) { m = x.z; c = 2; }
    if (x.w > m) { m = x.w; c = 3; }
    const float lmv = m;
    const int col = (hl << 2) + c;
    #pragma unroll
    for (int off = 1; off <= 16; off <<= 1) m = fmaxf(m, __shfl_xor(m, off));
    const unsigned long long b = __ballot(lmv == m);
    const int srcl = __ffs((unsigned)b) - 1;
    const int wcol = __shfl(col, srcl);
    float s = (__expf(x.x - m) + __expf(x.y - m)) +
              (__expf(x.z - m) + __expf(x.w - m));
    #pragma unroll
    for (int off = 1; off <= 16; off <<= 1) s += __shfl_xor(s, off);
    if (hl == 0) {
      const float conf = 1.0f / s;
      int bin = (int)ceilf(conf * 10.0f) - 1;
      bin = min(max(bin, 0), NBINS - 1);
      const unsigned long long acc = (targets[row] == wcol) ? 1ull : 0ull;
      const unsigned long long confq =
          (unsigned long long)((double)conf * 4294967296.0);
      atomicAdd(&sbins[bin], 1ull);
      atomicAdd(&sbins[NBINS + bin], confq);
      atomicAdd(&sbins[2 * NBINS + bin], acc);
    }
  }

  __syncthreads();
  for (int i = tid; i < 3 * NBINS; i += blockDim.x) {
    unsigned long long vv = sbins[i];
    if (vv) atomicAdd(&gbins[i], vv);  // relaxed device-scope, no fence
  }
}

__global__ void ece_final_kernel(const unsigned long long* __restrict__ gbins,
                                 float* __restrict__ out, int N) {
  const int t = threadIdx.x;
  float per = 0.0f;
  if (t < NBINS) {
    double cnt = (double)gbins[t];
    double sc = (double)gbins[NBINS + t] * (1.0 / 4294967296.0);
    double sa = (double)gbins[2 * NBINS + t];
    double safe = cnt > 0.0 ? cnt : 1.0;
    double avg_c = sc / safe;
    double avg_a = sa / safe;
    double prop = cnt / (double)N;
    per = (cnt > 0.0) ? (float)(fabs(avg_c - avg_a) * prop) : 0.0f;
  }
  #pragma unroll
  for (int off = 1; off < 16; off <<= 1) per += __shfl_xor(per, off);
  if (t == 0) out[0] = per;
}

extern "C" void kernel_launch(void* const* d_in, const int* in_sizes, int n_in,
                              void* d_out, int out_size, void* d_ws, size_t ws_size,
                              hipStream_t stream) {
  const float* logits = (const float*)d_in[0];
  const int* targets = (const int*)d_in[1];
  float* out = (float*)d_out;
  unsigned long long* gbins = (unsigned long long*)d_ws;

  const int N = in_sizes[1];  // 262144 rows

  hipMemsetAsync(gbins, 0, 3 * NBINS * sizeof(unsigned long long), stream);

  const int block = 256;  // 4 waves/block
  const int wavesPerBlock = block / 64;
  const int npairs = N >> 1;
  // one-shot: every wave gets exactly U pairs; no grid cap, no looping
  int grid = (npairs + wavesPerBlock * U - 1) / (wavesPerBlock * U);
  if (grid < 1) grid = 1;

  ece_main_kernel<<<grid, block, 0, stream>>>(logits, targets, gbins, N);
  ece_final_kernel<<<1, 64, 0, stream>>>(gbins, out, N);
}

// Round 6
// 39.094 us; speedup vs baseline: 6.7411x; 3.2058x over previous
//
#include <hip/hip_runtime.h>
#include <hip/hip_bf16.h>

#define NBINS 10
#define C 128
#define U 4        // pairs per wave-iteration
#define NREP 64    // gbins replicas (de-contend device-scope atomics)
#define REPSTRIDE 32  // u64 slots per replica (30 used, padded)

// d_ws layout: NREP replicas of [0..9] counts, [10..19] sum_conf (32.32 fixed),
//              [20..29] sum_acc  -- each replica REPSTRIDE u64 slots.

__global__ __launch_bounds__(256) void ece_main_kernel(
    const float* __restrict__ logits, const int* __restrict__ targets,
    unsigned long long* __restrict__ gbins, int N) {
  __shared__ unsigned long long sbins[3 * NBINS];
  const int tid = threadIdx.x;
  for (int i = tid; i < 3 * NBINS; i += blockDim.x) sbins[i] = 0ull;
  __syncthreads();

  const int lane = tid & 63;
  const int half = lane >> 5;   // which row of each pair this lane works on
  const int hl = lane & 31;     // lane index within the 32-lane half
  const int wavesPerBlock = blockDim.x >> 6;
  const int wid = blockIdx.x * wavesPerBlock + (tid >> 6);
  const int nwaves = gridDim.x * wavesPerBlock;

  const int npairs = N >> 1;

  for (int p0 = wid * U; p0 < npairs; p0 += nwaves * U) {
    float4 v[U];
    int pp[U];
    #pragma unroll
    for (int u = 0; u < U; ++u) {
      const int p = p0 + u;
      pp[u] = p < npairs ? p : npairs - 1;
      v[u] = *reinterpret_cast<const float4*>(
          logits + (size_t)pp[u] * (2 * C) + half * C + hl * 4);
    }

    // in-lane max + first-occurrence argmax over 4 elements
    float m[U], lm[U];
    int col[U];
    #pragma unroll
    for (int u = 0; u < U; ++u) {
      float mm = v[u].x; int c = 0;
      if (v[u].y > mm) { mm = v[u].y; c = 1; }
      if (v[u].z > mm) { mm = v[u].z; c = 2; }
      if (v[u].w > mm) { mm = v[u].w; c = 3; }
      m[u] = mm; lm[u] = mm; col[u] = (hl << 2) + c;
    }

    // half-wave value max: U independent DPP chains interleaved
    #pragma unroll
    for (int off = 1; off <= 16; off <<= 1) {
      #pragma unroll
      for (int u = 0; u < U; ++u) m[u] = fmaxf(m[u], __shfl_xor(m[u], off));
    }

    // first-occurrence argmax via ballot (lowest flagged lane in this half)
    int wcol[U];
    #pragma unroll
    for (int u = 0; u < U; ++u) {
      const unsigned long long b = __ballot(lm[u] == m[u]);
      const unsigned slice = (unsigned)(b >> (half << 5));
      const int srcl = (half << 5) + (__ffs(slice) - 1);
      wcol[u] = __shfl(col[u], srcl);
    }

    // sum of exp(x - max): independent exps, then U interleaved add chains
    float s[U];
    #pragma unroll
    for (int u = 0; u < U; ++u)
      s[u] = (__expf(v[u].x - m[u]) + __expf(v[u].y - m[u])) +
             (__expf(v[u].z - m[u]) + __expf(v[u].w - m[u]));
    #pragma unroll
    for (int off = 1; off <= 16; off <<= 1) {
      #pragma unroll
      for (int u = 0; u < U; ++u) s[u] += __shfl_xor(s[u], off);
    }

    #pragma unroll
    for (int u = 0; u < U; ++u) {
      if ((p0 + u) < npairs && hl == 0) {
        const float conf = 1.0f / s[u];            // = max(softmax(row))
        int bin = (int)ceilf(conf * 10.0f) - 1;    // (k/10,(k+1)/10] -> k
        bin = min(max(bin, 0), NBINS - 1);
        const int tgt = targets[pp[u] * 2 + half]; // only 2 lanes/wave load
        const unsigned long long acc = (tgt == wcol[u]) ? 1ull : 0ull;
        const unsigned long long confq =
            (unsigned long long)((double)conf * 4294967296.0);
        atomicAdd(&sbins[bin], 1ull);
        atomicAdd(&sbins[NBINS + bin], confq);
        atomicAdd(&sbins[2 * NBINS + bin], acc);
      }
    }
  }

  // odd-N leftover row (not hit for N=262144; kept for generality)
  if ((N & 1) && wid == 0 && half == 0) {
    const int row = N - 1;
    const float4 x = *reinterpret_cast<const float4*>(
        logits + (size_t)row * C + hl * 4);
    float m = x.x; int c = 0;
    if (x.y > m) { m = x.y; c = 1; }
    if (x.z > m) { m = x.z; c = 2; }
    if (x.w > m) { m = x.w; c = 3; }
    const float lmv = m;
    const int col = (hl << 2) + c;
    #pragma unroll
    for (int off = 1; off <= 16; off <<= 1) m = fmaxf(m, __shfl_xor(m, off));
    const unsigned long long b = __ballot(lmv == m);
    const int srcl = __ffs((unsigned)b) - 1;
    const int wcol = __shfl(col, srcl);
    float s = (__expf(x.x - m) + __expf(x.y - m)) +
              (__expf(x.z - m) + __expf(x.w - m));
    #pragma unroll
    for (int off = 1; off <= 16; off <<= 1) s += __shfl_xor(s, off);
    if (hl == 0) {
      const float conf = 1.0f / s;
      int bin = (int)ceilf(conf * 10.0f) - 1;
      bin = min(max(bin, 0), NBINS - 1);
      const unsigned long long acc = (targets[row] == wcol) ? 1ull : 0ull;
      const unsigned long long confq =
          (unsigned long long)((double)conf * 4294967296.0);
      atomicAdd(&sbins[bin], 1ull);
      atomicAdd(&sbins[NBINS + bin], confq);
      atomicAdd(&sbins[2 * NBINS + bin], acc);
    }
  }

  // flush block partials into this block's replica (low-contention atomics)
  __syncthreads();
  unsigned long long* rep = gbins + (size_t)(blockIdx.x & (NREP - 1)) * REPSTRIDE;
  for (int i = tid; i < 3 * NBINS; i += blockDim.x) {
    unsigned long long vv = sbins[i];
    if (vv) atomicAdd(&rep[i], vv);
  }
}

__global__ void ece_final_kernel(const unsigned long long* __restrict__ gbins,
                                 float* __restrict__ out, int N) {
  __shared__ unsigned long long tot[3 * NBINS];
  const int t = threadIdx.x;  // 64 threads
  if (t < 3 * NBINS) {
    unsigned long long s = 0ull;
    #pragma unroll 8
    for (int r = 0; r < NREP; ++r) s += gbins[(size_t)r * REPSTRIDE + t];
    tot[t] = s;
  }
  __syncthreads();
  float per = 0.0f;
  if (t < NBINS) {
    const double cnt = (double)tot[t];
    const double sc = (double)tot[NBINS + t] * (1.0 / 4294967296.0);
    const double sa = (double)tot[2 * NBINS + t];
    const double safe = cnt > 0.0 ? cnt : 1.0;
    const double avg_c = sc / safe;
    const double avg_a = sa / safe;
    const double prop = cnt / (double)N;
    per = (cnt > 0.0) ? (float)(fabs(avg_c - avg_a) * prop) : 0.0f;
  }
  #pragma unroll
  for (int off = 1; off < 16; off <<= 1) per += __shfl_xor(per, off);
  if (t == 0) out[0] = per;
}

extern "C" void kernel_launch(void* const* d_in, const int* in_sizes, int n_in,
                              void* d_out, int out_size, void* d_ws, size_t ws_size,
                              hipStream_t stream) {
  const float* logits = (const float*)d_in[0];
  const int* targets = (const int*)d_in[1];
  float* out = (float*)d_out;
  unsigned long long* gbins = (unsigned long long*)d_ws;

  const int N = in_sizes[1];  // 262144 rows

  // zero all replicas (NREP * REPSTRIDE u64 = 16 KB)
  hipMemsetAsync(gbins, 0, NREP * REPSTRIDE * sizeof(unsigned long long),
                 stream);

  const int block = 256;  // 4 waves/block
  const int wavesPerBlock = block / 64;
  const int npairs = N >> 1;
  int grid = 2048;        // grid-stride: 4 iterations/wave at N=262144
  int maxGrid = (npairs + wavesPerBlock * U - 1) / (wavesPerBlock * U);
  if (grid > maxGrid) grid = maxGrid > 0 ? maxGrid : 1;

  ece_main_kernel<<<grid, block, 0, stream>>>(logits, targets, gbins, N);
  ece_final_kernel<<<1, 64, 0, stream>>>(gbins, out, N);
}